// Round 3
// baseline (329.358 us; speedup 1.0000x reference)
//
#include <hip/hip_runtime.h>
#include <stdint.h>
#include <math.h>

// RPN proposal filtering: decode -> clip -> validity mask -> stable top-2000
// -> greedy NMS (IoU > 0.7) -> first 1000 kept -> (B, 1000, 5).
//
// R9: k_scanout accumulate made BRANCHLESS. R8's conditional
// `if(keptbits>>j&1) removed|=m[j]` let the compiler sink each m[j] load into
// its branch (VGPR_Count=76 proved m[64] never lived in registers), putting a
// dependent global load + vmcnt(0) on the serial chain per kept row
// (~400cyc x ~1000 rows ~= the observed 77us). Now
// `removed |= m[j] & (-(keptbits>>j & 1))` makes every load unconditionally
// needed: loads stay hoisted at chunk top (VGPR should jump to ~160+),
// latency hides under the ffs scan, accumulate is pure SALU+VALU.

#define IMGF 1024.0f
#define PRE_NMS 2000
#define POST_NMS 1000
#define NMS_THR 0.7f
#define MIN_SZ 16.0f
#define CAP 4096          // candidate buffer per batch
#define SEL 2048          // padded selection stride (>= PRE_NMS)
#define NW (SEL / 64)     // 32 mask words per row
#define CNT_STRIDE 32     // u32s per batch for counters (128 B -> own line)
#define KEY_NEGINF 0x007FFFFFu  // f2key(-inf)
#define MAXCHUNK 12

// Order-preserving float -> u32 key (all floats incl. -inf totally ordered).
__device__ __forceinline__ uint32_t f2key(float f) {
  uint32_t u = __float_as_uint(f);
  return (u & 0x80000000u) ? ~u : (u | 0x80000000u);
}
__device__ __forceinline__ float key2f(uint32_t k) {
  uint32_t u = (k & 0x80000000u) ? (k & 0x7FFFFFFFu) : ~k;
  return __uint_as_float(u);
}

__device__ __forceinline__ unsigned long long readlane_u64(unsigned long long v,
                                                           int lane) {
  unsigned int lo = __builtin_amdgcn_readlane((unsigned int)v, lane);
  unsigned int hi = __builtin_amdgcn_readlane((unsigned int)(v >> 32), lane);
  return ((unsigned long long)hi << 32) | lo;
}

// Mirrors reference _decode + clip, fp32.
__device__ __forceinline__ float4 decode_clip(float4 anc, float4 dlt) {
  float aw = anc.z - anc.x;
  float ah = anc.w - anc.y;
  float ax = anc.x + 0.5f * aw;
  float ay = anc.y + 0.5f * ah;
  float dw = fminf(dlt.z, 4.0f);
  float dh = fminf(dlt.w, 4.0f);
  float px = dlt.x * aw + ax;
  float py = dlt.y * ah + ay;
  float pw = expf(dw) * aw;
  float ph = expf(dh) * ah;
  float x1 = px - 0.5f * pw, y1 = py - 0.5f * ph;
  float x2 = px + 0.5f * pw, y2 = py + 0.5f * ph;
  x1 = fminf(fmaxf(x1, 0.0f), IMGF);
  y1 = fminf(fmaxf(y1, 0.0f), IMGF);
  x2 = fminf(fmaxf(x2, 0.0f), IMGF);
  y2 = fminf(fmaxf(y2, 0.0f), IMGF);
  return make_float4(x1, y1, x2, y2);
}

// K1: decode -> masked-score key; per-block LDS coarse hist of key>>24
// (finite keys only), ballot-match wave aggregation, one aggregated global
// flush per block. grid = (bpb, B).
__global__ void k_decode(const float4* __restrict__ anchors,
                         const float4* __restrict__ deltas,
                         const float* __restrict__ scores,
                         uint32_t* __restrict__ keys,
                         uint32_t* __restrict__ chist,
                         int A, int chunks) {
  int b = blockIdx.y;
  int t = threadIdx.x;  // 256
  int lane = t & 63;
  __shared__ uint32_t shist[256];
  shist[t] = 0;
  __syncthreads();
  int base_a = blockIdx.x * (chunks * 256);
  for (int c = 0; c < chunks; c++) {
    int a = base_a + c * 256 + t;
    bool inb = a < A;
    int ac = inb ? a : (A - 1);
    size_t i = (size_t)b * A + ac;
    float4 box = decode_clip(anchors[ac], deltas[i]);
    bool valid = (box.z - box.x >= MIN_SZ) && (box.w - box.y >= MIN_SZ);
    float ms = valid ? scores[i] : -INFINITY;
    uint32_t k = f2key(ms);
    if (inb) keys[i] = k;
    uint32_t bucket = k >> 24;
    bool fin = inb && (k != KEY_NEGINF);
    // lanes with equal bucket -> one LDS atomic by the leader
    unsigned long long match = __ballot(fin);
#pragma unroll
    for (int bit = 0; bit < 8; bit++) {
      bool hb = (bucket >> bit) & 1;
      unsigned long long bb = __ballot(hb && fin);
      match &= hb ? bb : ~bb;
    }
    if (fin && (__ffsll((long long)match) - 1 == lane))
      atomicAdd(&shist[bucket], (uint32_t)__popcll(match));
  }
  __syncthreads();
  uint32_t v = shist[t];
  if (v) atomicAdd(&chist[b * 256 + t], v);
}

// K2: pick coarse bucket cb s.t. countAbove(cb) < PRE_NMS <= countAbove(cb)+chist[cb].
__global__ void k_coarse(const uint32_t* __restrict__ chist,
                         int* __restrict__ cbArr,
                         uint32_t* __restrict__ cumArr) {
  int b = blockIdx.x;
  int t = threadIdx.x;  // 256
  __shared__ uint32_t sA[256];
  sA[t] = chist[b * 256 + t];
  for (int d = 1; d < 256; d <<= 1) {  // inclusive suffix scan
    __syncthreads();
    uint32_t v = sA[t] + ((t + d < 256) ? sA[t + d] : 0u);
    __syncthreads();
    sA[t] = v;
  }
  __syncthreads();
  if (t == 0 && sA[0] < PRE_NMS) {  // degenerate: < PRE_NMS finite entries
    cbArr[b] = -1;
    cumArr[b] = 0;
  }
  uint32_t nxt = (t < 255) ? sA[t + 1] : 0u;
  if (sA[t] >= PRE_NMS && nxt < PRE_NMS) {
    cbArr[b] = t;
    cumArr[b] = nxt;  // count strictly above coarse bucket t
  }
}

// K3: fine hist of key bits[23:16] for elements whose coarse bucket == cb[b].
__global__ void k_fine(const uint32_t* __restrict__ keys,
                       const int* __restrict__ cbArr,
                       uint32_t* __restrict__ fhist,
                       int A, int chunks) {
  int b = blockIdx.y;
  int t = threadIdx.x;  // 256
  int cb = cbArr[b];
  if (cb < 0) return;
  __shared__ uint32_t shist[256];
  shist[t] = 0;
  __syncthreads();
  int base_a = blockIdx.x * (chunks * 256);
  uint32_t cbu = (uint32_t)cb;
  for (int c = 0; c < chunks; c++) {
    int a = base_a + c * 256 + t;
    if (a >= A) break;
    uint32_t k = keys[(size_t)b * A + a];
    if ((k >> 24) == cbu && k != KEY_NEGINF)
      atomicAdd(&shist[(k >> 16) & 0xFFu], 1u);
  }
  __syncthreads();
  uint32_t v = shist[t];
  if (v) atomicAdd(&fhist[b * 256 + t], v);
}

// K4: final 16-bit threshold beta = (cb<<8)|d:
// count(key>>16 > beta) < PRE_NMS <= count(key>>16 >= beta), finite keys only.
__global__ void k_thresh(const uint32_t* __restrict__ fhist,
                         const int* __restrict__ cbArr,
                         const uint32_t* __restrict__ cumArr,
                         uint32_t* __restrict__ thresh,
                         uint32_t* __restrict__ cnts) {
  int b = blockIdx.x;
  int t = threadIdx.x;  // 256
  __shared__ uint32_t sA[256];
  if (t < 2) cnts[b * CNT_STRIDE + t] = 0;
  int cb = cbArr[b];
  if (cb < 0) {
    if (t == 0) thresh[b] = 0u;
    return;
  }
  uint32_t cumAbove = cumArr[b];
  sA[t] = fhist[b * 256 + t];
  for (int d = 1; d < 256; d <<= 1) {
    __syncthreads();
    uint32_t v = sA[t] + ((t + d < 256) ? sA[t + d] : 0u);
    __syncthreads();
    sA[t] = v;
  }
  __syncthreads();
  uint32_t nxt = (t < 255) ? sA[t + 1] : 0u;
  if (cumAbove + sA[t] >= PRE_NMS && cumAbove + nxt < PRE_NMS)
    thresh[b] = (uint32_t)((cb << 8) | t);
}

// K5: gather candidate KEYS ONLY (8B each), block-aggregated atomics: one
// atomicAdd per category per block. Strictly-above fills [0, c1); ties fill
// from CAP-1 downward; overflow ties dropped (only above 2096 ties/batch).
__global__ void k_gather(const uint32_t* __restrict__ keys,
                         const uint32_t* __restrict__ thresh,
                         uint32_t* __restrict__ cnts,
                         unsigned long long* __restrict__ cand_sort,
                         int A, int chunks) {
  int b = blockIdx.y;
  int t = threadIdx.x;  // 256
  int lane = t & 63;
  int w = t >> 6;  // wave 0..3
  __shared__ unsigned long long s_mA[MAXCHUNK * 4], s_mT[MAXCHUNK * 4];
  __shared__ uint32_t s_offA[MAXCHUNK * 4], s_offT[MAXCHUNK * 4];
  __shared__ uint32_t s_cA[MAXCHUNK * 4], s_cT[MAXCHUNK * 4];
  __shared__ uint32_t s_baseA, s_baseT;
  uint32_t beta = thresh[b];
  uint32_t kreg[MAXCHUNK];
  int base_a = blockIdx.x * (chunks * 256);
  for (int c = 0; c < chunks; c++) {
    int a = base_a + c * 256 + t;
    bool inb = a < A;
    uint32_t k = inb ? keys[(size_t)b * A + a] : KEY_NEGINF;
    kreg[c] = k;
    uint32_t bk = k >> 16;
    bool fin = (k != KEY_NEGINF);
    unsigned long long mA = __ballot(fin && (bk > beta));
    unsigned long long mT = __ballot(fin && (bk == beta));
    if (lane == 0) {
      s_mA[c * 4 + w] = mA;
      s_mT[c * 4 + w] = mT;
    }
  }
  __syncthreads();
  if (t < chunks * 4) {
    s_cA[t] = (uint32_t)__popcll(s_mA[t]);
    s_cT[t] = (uint32_t)__popcll(s_mT[t]);
  }
  __syncthreads();
  if (t == 0) {  // serial scan over <=44 entries, then ONE atomic per category
    uint32_t accA = 0, accT = 0;
    for (int id = 0; id < chunks * 4; id++) {
      s_offA[id] = accA;
      accA += s_cA[id];
      s_offT[id] = accT;
      accT += s_cT[id];
    }
    s_baseA = accA ? atomicAdd(&cnts[b * CNT_STRIDE + 0], accA) : 0u;
    s_baseT = accT ? atomicAdd(&cnts[b * CNT_STRIDE + 1], accT) : 0u;
  }
  __syncthreads();
  uint32_t baseA = s_baseA, baseT = s_baseT;
  unsigned long long lower = ((unsigned long long)1 << lane) - 1;
  for (int c = 0; c < chunks; c++) {
    int id = c * 4 + w;
    unsigned long long mA = s_mA[id], mT = s_mT[id];
    bool above = (mA >> lane) & 1;
    bool tie = (mT >> lane) & 1;
    if (!(above || tie)) continue;
    int pos;
    if (above) {
      pos = (int)(baseA + s_offA[id] + (uint32_t)__popcll(mA & lower));
      if (pos >= PRE_NMS) continue;  // defensive; cannot happen
    } else {
      pos = CAP - 1 - (int)(baseT + s_offT[id] + (uint32_t)__popcll(mT & lower));
      if (pos < PRE_NMS) continue;  // drop overflow ties
    }
    int a = base_a + c * 256 + t;
    // sort key: (score_key desc, anchor index asc) via descending u64 order
    cand_sort[(size_t)b * CAP + pos] =
        ((unsigned long long)kreg[c] << 32) | (uint32_t)(~(uint32_t)a);
  }
}

// K6a: default-fill selection (pads for degenerate batches; overwritten by
// k_rank for every live rank < SEL). grid = (SEL/256, B).
__global__ void k_fillsel(float4* __restrict__ sel_box,
                          float* __restrict__ sel_score) {
  int b = blockIdx.y;
  int r = blockIdx.x * 256 + threadIdx.x;
  sel_score[(size_t)b * SEL + r] = -INFINITY;
  sel_box[(size_t)b * SEL + r] = make_float4(0.0f, 0.0f, 0.0f, 0.0f);
}

// K6b: enumeration sort. Keys are strictly distinct ((score_key, ~anchor)),
// so rank = #{keys > mine} is the exact descending-sorted position. Each
// thread owns one slot, streams the batch's live slots through LDS broadcast
// tiles, and (if rank < SEL) decodes its box from the embedded anchor index.
// grid = (CAP/256, B). Fully parallel: 256 blocks, no cross-thread deps.
__global__ void k_rank(const unsigned long long* __restrict__ cand_sort,
                       const uint32_t* __restrict__ cnts,
                       const float4* __restrict__ anchors,
                       const float4* __restrict__ deltas,
                       float4* __restrict__ sel_box,
                       float* __restrict__ sel_score, int A) {
  int b = blockIdx.y;
  int t = threadIdx.x;  // 256
  uint32_t c1 = cnts[b * CNT_STRIDE + 0];
  if (c1 > PRE_NMS) c1 = PRE_NMS;
  uint32_t c2 = cnts[b * CNT_STRIDE + 1];
  if (c2 > CAP - PRE_NMS) c2 = CAP - PRE_NMS;
  int loTie = CAP - (int)c2;
  int bs = blockIdx.x * 256;
  if (bs >= (int)c1 && bs + 256 <= loTie) return;  // block fully in dead gap
  int s = bs + t;
  bool live = (s < (int)c1) || (s >= loTie);
  unsigned long long myKey = live ? cand_sort[(size_t)b * CAP + s] : 0ull;
  __shared__ unsigned long long tile[256];
  int rank = 0;
  for (int ts = 0; ts < CAP; ts += 256) {  // tile-skip is block-uniform
    if (ts >= (int)c1 && ts + 256 <= loTie) continue;
    int idx = ts + t;
    bool lv = (idx < (int)c1) || (idx >= loTie);
    __syncthreads();
    tile[t] = lv ? cand_sort[(size_t)b * CAP + idx] : 0ull;
    __syncthreads();
    if (live) {
#pragma unroll 8
      for (int j = 0; j < 256; j++) rank += (tile[j] > myKey) ? 1 : 0;
    }
  }
  if (live && rank < SEL) {
    uint32_t a = ~((uint32_t)myKey);
    float4 box = decode_clip(anchors[a], deltas[(size_t)b * A + a]);
    sel_score[(size_t)b * SEL + rank] = key2f((uint32_t)(myKey >> 32));
    sel_box[(size_t)b * SEL + rank] = box;
  }
}

// K7: suppression bitmask. mask[b][i][jb] bit jj set iff j = jb*64+jj > i,
// j < PRE_NMS, IoU(box_i, box_j) > NMS_THR. Rows in [PRE_NMS, SEL) zeroed
// so k_scanout never reads unwritten workspace.
__global__ void k_nmsmask(const float4* __restrict__ sel_box,
                          unsigned long long* __restrict__ mask) {
  int jb = blockIdx.x;  // col block
  int ib = blockIdx.y;  // row block
  int b = blockIdx.z;
  int t = threadIdx.x;  // 64
  int i = ib * 64 + t;
  if (jb < ib) {  // uniform per block; entire col tile is <= all rows
    mask[((size_t)b * SEL + i) * NW + jb] = 0ull;
    return;
  }
  __shared__ float4 cb[64];
  __shared__ float careb[64];
  int j0 = jb * 64;
  float4 cbx = sel_box[(size_t)b * SEL + j0 + t];
  cb[t] = cbx;
  careb[t] = (cbx.z - cbx.x) * (cbx.w - cbx.y);
  __syncthreads();
  if (i >= PRE_NMS) {  // pad rows: write zeros, never leave stale poison
    mask[((size_t)b * SEL + i) * NW + jb] = 0ull;
    return;
  }
  float4 a = sel_box[(size_t)b * SEL + i];
  float area_a = (a.z - a.x) * (a.w - a.y);
  unsigned long long bits = 0ull;
  int jmax = min(64, PRE_NMS - j0);
  for (int jj = 0; jj < jmax; jj++) {
    int j = j0 + jj;
    if (j <= i) continue;
    float4 bb = cb[jj];
    float ltx = fmaxf(a.x, bb.x), lty = fmaxf(a.y, bb.y);
    float rbx = fminf(a.z, bb.z), rby = fminf(a.w, bb.w);
    float w = fmaxf(rbx - ltx, 0.0f), hgt = fmaxf(rby - lty, 0.0f);
    float inter = w * hgt;
    float iou = inter / (area_a + careb[jj] - inter + 1e-6f);
    if (iou > NMS_THR) bits |= (1ull << jj);
  }
  mask[((size_t)b * SEL + i) * NW + jb] = bits;
}

// K8: one wave per batch. ffs-driven greedy scan: only ALIVE rows are
// visited. Per chunk of 64 rows:
//   diag  = per-lane current-chunk word of each row (lane r owns row r)
//   curw  = removed word for this chunk at entry
//   work  = ~curw & range; loop: r=ffs(work); curw|=readlane(diag,r);
//           work &= ~(curw|bits<=r). Suppressed rows never visited.
//   keptbits -> lane-parallel keptList append (popcount rank) + kc update.
//   removed |= kept rows' words: BRANCHLESS masked OR over all 64 preloaded
//   row-words (uniform SGPR mask per row) -> loads stay hoisted/unconditional.
__global__ void __launch_bounds__(64, 1)
k_scanout(const float4* __restrict__ sel_box,
          const float* __restrict__ sel_score,
          const unsigned long long* __restrict__ mask,
          float* __restrict__ out) {
  int b = blockIdx.x;
  int t = threadIdx.x;  // 64 = 1 wave
  int tw = t & 31;
  __shared__ uint32_t keptList[POST_NMS + 64];  // overshoot space
  unsigned long long removed = 0ull;  // lane w<32 owns word w (dup in w+32)
  int kc = 0;
  const unsigned long long* mbase = mask + (size_t)b * SEL * NW;
  const int lastChunk = (PRE_NMS - 1) / 64;  // 31
  for (int chunk = 0; chunk <= lastChunk; chunk++) {
    int rmax = PRE_NMS - chunk * 64;  // rows beyond PRE_NMS excluded
    if (rmax > 64) rmax = 64;
    // per-lane diag word: row (chunk*64 + t), word index = chunk
    unsigned long long diag = mbase[((size_t)(chunk * 64 + t)) * NW + chunk];
    // preload all 64 row-words of this chunk (word tw per lane); consumed
    // only AFTER the serial scan (branchlessly) -> latency hidden under it.
    const unsigned long long* cbase = mbase + (size_t)chunk * 64 * NW;
    unsigned long long m[64];
#pragma unroll
    for (int j = 0; j < 64; j++) m[j] = cbase[j * NW + tw];
    // score validity for all 64 rows in one ballot
    uint32_t scb =
        __float_as_uint(sel_score[(size_t)b * SEL + chunk * 64 + t]);
    unsigned long long vb = __ballot(scb != 0xFF800000u);
    // entry removed word for this chunk
    unsigned long long curw = readlane_u64(removed, chunk);
    unsigned long long range =
        (rmax >= 64) ? ~0ull : ((1ull << rmax) - 1ull);
    unsigned long long work = ~curw & range;
    unsigned long long keptbits = 0ull;
    while (work) {
      int r = __ffsll((long long)work) - 1;
      keptbits |= (1ull << r);
      unsigned long long d = readlane_u64(diag, r);
      curw |= d;
      unsigned long long low = (2ull << r) - 1ull;  // bits 0..r (r=63 ok)
      work &= ~(curw | low);
    }
    // bookkeeping (off the serial chain)
    unsigned long long kv = keptbits & vb;
    if ((kv >> t) & 1ull) {
      int rank = (int)__popcll(kv & ((1ull << t) - 1ull));
      keptList[kc + rank] = (uint32_t)(chunk * 64 + t);
    }
    kc += (int)__popcll(kv);
    if (kc >= POST_NMS) break;           // future chunks irrelevant
    if (chunk == lastChunk) break;       // no future chunks
    // accumulate removed: BRANCHLESS masked OR (mask is uniform SGPR value),
    // so every m[j] is unconditionally live -> loads cannot be sunk.
    uint32_t klo = (uint32_t)keptbits;
    uint32_t khi = (uint32_t)(keptbits >> 32);
#pragma unroll
    for (int j = 0; j < 32; j++) {
      unsigned long long mk =
          (unsigned long long)(-(long long)((klo >> j) & 1u));
      removed |= m[j] & mk;
    }
#pragma unroll
    for (int j = 0; j < 32; j++) {
      unsigned long long mk =
          (unsigned long long)(-(long long)((khi >> j) & 1u));
      removed |= m[32 + j] & mk;
    }
  }
  int kcc = kc < POST_NMS ? kc : POST_NMS;
  __syncthreads();
  for (int r = t; r < POST_NMS; r += 64) {
    float4 bx = make_float4(0.0f, 0.0f, 0.0f, 0.0f);
    float sc = 0.0f;
    if (r < kcc) {
      int i = (int)keptList[r];
      bx = sel_box[(size_t)b * SEL + i];
      sc = sel_score[(size_t)b * SEL + i];
    }
    float* o = out + ((size_t)b * POST_NMS + r) * 5;
    o[0] = bx.x;
    o[1] = bx.y;
    o[2] = bx.z;
    o[3] = bx.w;
    o[4] = sc;
  }
}

extern "C" void kernel_launch(void* const* d_in, const int* in_sizes, int n_in,
                              void* d_out, int out_size, void* d_ws, size_t ws_size,
                              hipStream_t stream) {
  const float* anchors = (const float*)d_in[0];  // (A, 4)
  const float* deltas = (const float*)d_in[1];   // (B, A, 4)
  const float* scores = (const float*)d_in[2];   // (B, A)
  int A = in_sizes[0] / 4;
  int BA = in_sizes[2];
  int B = BA / A;
  float* out = (float*)d_out;

  char* ws = (char*)d_ws;
  size_t off = 0;
  uint32_t* keys = (uint32_t*)(ws + off);
  off += (size_t)BA * 4;
  uint32_t* chist = (uint32_t*)(ws + off);
  off += (size_t)B * 256 * 4;
  uint32_t* fhist = (uint32_t*)(ws + off);
  off += (size_t)B * 256 * 4;
  int* cbArr = (int*)(ws + off);
  off += (size_t)B * 4;
  uint32_t* cumArr = (uint32_t*)(ws + off);
  off += (size_t)B * 4;
  uint32_t* thresh = (uint32_t*)(ws + off);
  off += (size_t)B * 4;
  off = (off + 127) & ~(size_t)127;
  uint32_t* cnts = (uint32_t*)(ws + off);
  off += (size_t)B * CNT_STRIDE * 4;
  off = (off + 15) & ~(size_t)15;
  unsigned long long* cand_sort = (unsigned long long*)(ws + off);
  off += (size_t)B * CAP * 8;
  float4* sel_box = (float4*)(ws + off);
  off += (size_t)B * SEL * 16;
  float* sel_score = (float*)(ws + off);
  off += (size_t)B * SEL * 4;
  unsigned long long* mask = (unsigned long long*)(ws + off);
  off += (size_t)B * SEL * NW * 8;
  // total ~27 MB

  // Block geometry for per-batch streaming kernels: A = 261888 = 256*11*93.
  int chunks = (A % (256 * 11) == 0) ? 11 : 1;
  int bpb = (A + 256 * chunks - 1) / (256 * chunks);  // blocks per batch

  hipMemsetAsync(chist, 0, (size_t)B * 256 * 4 * 2, stream);  // chist+fhist
  k_decode<<<dim3(bpb, B), 256, 0, stream>>>((const float4*)anchors,
                                             (const float4*)deltas, scores,
                                             keys, chist, A, chunks);
  k_coarse<<<B, 256, 0, stream>>>(chist, cbArr, cumArr);
  k_fine<<<dim3(bpb, B), 256, 0, stream>>>(keys, cbArr, fhist, A, chunks);
  k_thresh<<<B, 256, 0, stream>>>(fhist, cbArr, cumArr, thresh, cnts);
  k_gather<<<dim3(bpb, B), 256, 0, stream>>>(keys, thresh, cnts, cand_sort, A,
                                             chunks);
  k_fillsel<<<dim3(SEL / 256, B), 256, 0, stream>>>(sel_box, sel_score);
  k_rank<<<dim3(CAP / 256, B), 256, 0, stream>>>(cand_sort, cnts,
                                                 (const float4*)anchors,
                                                 (const float4*)deltas,
                                                 sel_box, sel_score, A);
  k_nmsmask<<<dim3(NW, SEL / 64, B), 64, 0, stream>>>(sel_box, mask);
  k_scanout<<<B, 64, 0, stream>>>(sel_box, sel_score, mask, out);
}

// Round 4
// 326.946 us; speedup vs baseline: 1.0074x; 1.0074x over previous
//
#include <hip/hip_runtime.h>
#include <stdint.h>
#include <math.h>

// RPN proposal filtering: decode -> clip -> validity mask -> stable top-2000
// -> greedy NMS (IoU > 0.7) -> first 1000 kept -> (B, 1000, 5).
//
// R10: k_scanout mask tile staged through LDS-DMA. R8/R9 proved (identical
// 76.7us, VGPR=76 both rounds) that the compiler refuses to keep a 64xu64
// staging array in VGPRs: it sinks the loads and batches them ~10 at a time,
// paying ~6 serialized HBM waits per chunk. global_load_lds is side-effecting
// (cannot be sunk), uses zero VGPRs, and lands the 16KB chunk tile in LDS
// while the ffs scan runs. diag/score for chunk c+1 are prefetched during
// chunk c, so the scan itself starts with zero memory waits. Accumulate
// reads the tile via ds_read_b64 (2-way bank aliasing = free) under uniform
// SGPR masks (branchless).

#define IMGF 1024.0f
#define PRE_NMS 2000
#define POST_NMS 1000
#define NMS_THR 0.7f
#define MIN_SZ 16.0f
#define CAP 4096          // candidate buffer per batch
#define SEL 2048          // padded selection stride (>= PRE_NMS)
#define NW (SEL / 64)     // 32 mask words per row
#define CNT_STRIDE 32     // u32s per batch for counters (128 B -> own line)
#define KEY_NEGINF 0x007FFFFFu  // f2key(-inf)
#define MAXCHUNK 12

// Order-preserving float -> u32 key (all floats incl. -inf totally ordered).
__device__ __forceinline__ uint32_t f2key(float f) {
  uint32_t u = __float_as_uint(f);
  return (u & 0x80000000u) ? ~u : (u | 0x80000000u);
}
__device__ __forceinline__ float key2f(uint32_t k) {
  uint32_t u = (k & 0x80000000u) ? (k & 0x7FFFFFFFu) : ~k;
  return __uint_as_float(u);
}

__device__ __forceinline__ unsigned long long readlane_u64(unsigned long long v,
                                                           int lane) {
  unsigned int lo = __builtin_amdgcn_readlane((unsigned int)v, lane);
  unsigned int hi = __builtin_amdgcn_readlane((unsigned int)(v >> 32), lane);
  return ((unsigned long long)hi << 32) | lo;
}

// Mirrors reference _decode + clip, fp32.
__device__ __forceinline__ float4 decode_clip(float4 anc, float4 dlt) {
  float aw = anc.z - anc.x;
  float ah = anc.w - anc.y;
  float ax = anc.x + 0.5f * aw;
  float ay = anc.y + 0.5f * ah;
  float dw = fminf(dlt.z, 4.0f);
  float dh = fminf(dlt.w, 4.0f);
  float px = dlt.x * aw + ax;
  float py = dlt.y * ah + ay;
  float pw = expf(dw) * aw;
  float ph = expf(dh) * ah;
  float x1 = px - 0.5f * pw, y1 = py - 0.5f * ph;
  float x2 = px + 0.5f * pw, y2 = py + 0.5f * ph;
  x1 = fminf(fmaxf(x1, 0.0f), IMGF);
  y1 = fminf(fmaxf(y1, 0.0f), IMGF);
  x2 = fminf(fmaxf(x2, 0.0f), IMGF);
  y2 = fminf(fmaxf(y2, 0.0f), IMGF);
  return make_float4(x1, y1, x2, y2);
}

// K1: decode -> masked-score key; per-block LDS coarse hist of key>>24
// (finite keys only), ballot-match wave aggregation, one aggregated global
// flush per block. grid = (bpb, B).
__global__ void k_decode(const float4* __restrict__ anchors,
                         const float4* __restrict__ deltas,
                         const float* __restrict__ scores,
                         uint32_t* __restrict__ keys,
                         uint32_t* __restrict__ chist,
                         int A, int chunks) {
  int b = blockIdx.y;
  int t = threadIdx.x;  // 256
  int lane = t & 63;
  __shared__ uint32_t shist[256];
  shist[t] = 0;
  __syncthreads();
  int base_a = blockIdx.x * (chunks * 256);
  for (int c = 0; c < chunks; c++) {
    int a = base_a + c * 256 + t;
    bool inb = a < A;
    int ac = inb ? a : (A - 1);
    size_t i = (size_t)b * A + ac;
    float4 box = decode_clip(anchors[ac], deltas[i]);
    bool valid = (box.z - box.x >= MIN_SZ) && (box.w - box.y >= MIN_SZ);
    float ms = valid ? scores[i] : -INFINITY;
    uint32_t k = f2key(ms);
    if (inb) keys[i] = k;
    uint32_t bucket = k >> 24;
    bool fin = inb && (k != KEY_NEGINF);
    // lanes with equal bucket -> one LDS atomic by the leader
    unsigned long long match = __ballot(fin);
#pragma unroll
    for (int bit = 0; bit < 8; bit++) {
      bool hb = (bucket >> bit) & 1;
      unsigned long long bb = __ballot(hb && fin);
      match &= hb ? bb : ~bb;
    }
    if (fin && (__ffsll((long long)match) - 1 == lane))
      atomicAdd(&shist[bucket], (uint32_t)__popcll(match));
  }
  __syncthreads();
  uint32_t v = shist[t];
  if (v) atomicAdd(&chist[b * 256 + t], v);
}

// K2: pick coarse bucket cb s.t. countAbove(cb) < PRE_NMS <= countAbove(cb)+chist[cb].
__global__ void k_coarse(const uint32_t* __restrict__ chist,
                         int* __restrict__ cbArr,
                         uint32_t* __restrict__ cumArr) {
  int b = blockIdx.x;
  int t = threadIdx.x;  // 256
  __shared__ uint32_t sA[256];
  sA[t] = chist[b * 256 + t];
  for (int d = 1; d < 256; d <<= 1) {  // inclusive suffix scan
    __syncthreads();
    uint32_t v = sA[t] + ((t + d < 256) ? sA[t + d] : 0u);
    __syncthreads();
    sA[t] = v;
  }
  __syncthreads();
  if (t == 0 && sA[0] < PRE_NMS) {  // degenerate: < PRE_NMS finite entries
    cbArr[b] = -1;
    cumArr[b] = 0;
  }
  uint32_t nxt = (t < 255) ? sA[t + 1] : 0u;
  if (sA[t] >= PRE_NMS && nxt < PRE_NMS) {
    cbArr[b] = t;
    cumArr[b] = nxt;  // count strictly above coarse bucket t
  }
}

// K3: fine hist of key bits[23:16] for elements whose coarse bucket == cb[b].
__global__ void k_fine(const uint32_t* __restrict__ keys,
                       const int* __restrict__ cbArr,
                       uint32_t* __restrict__ fhist,
                       int A, int chunks) {
  int b = blockIdx.y;
  int t = threadIdx.x;  // 256
  int cb = cbArr[b];
  if (cb < 0) return;
  __shared__ uint32_t shist[256];
  shist[t] = 0;
  __syncthreads();
  int base_a = blockIdx.x * (chunks * 256);
  uint32_t cbu = (uint32_t)cb;
  for (int c = 0; c < chunks; c++) {
    int a = base_a + c * 256 + t;
    if (a >= A) break;
    uint32_t k = keys[(size_t)b * A + a];
    if ((k >> 24) == cbu && k != KEY_NEGINF)
      atomicAdd(&shist[(k >> 16) & 0xFFu], 1u);
  }
  __syncthreads();
  uint32_t v = shist[t];
  if (v) atomicAdd(&fhist[b * 256 + t], v);
}

// K4: final 16-bit threshold beta = (cb<<8)|d:
// count(key>>16 > beta) < PRE_NMS <= count(key>>16 >= beta), finite keys only.
__global__ void k_thresh(const uint32_t* __restrict__ fhist,
                         const int* __restrict__ cbArr,
                         const uint32_t* __restrict__ cumArr,
                         uint32_t* __restrict__ thresh,
                         uint32_t* __restrict__ cnts) {
  int b = blockIdx.x;
  int t = threadIdx.x;  // 256
  __shared__ uint32_t sA[256];
  if (t < 2) cnts[b * CNT_STRIDE + t] = 0;
  int cb = cbArr[b];
  if (cb < 0) {
    if (t == 0) thresh[b] = 0u;
    return;
  }
  uint32_t cumAbove = cumArr[b];
  sA[t] = fhist[b * 256 + t];
  for (int d = 1; d < 256; d <<= 1) {
    __syncthreads();
    uint32_t v = sA[t] + ((t + d < 256) ? sA[t + d] : 0u);
    __syncthreads();
    sA[t] = v;
  }
  __syncthreads();
  uint32_t nxt = (t < 255) ? sA[t + 1] : 0u;
  if (cumAbove + sA[t] >= PRE_NMS && cumAbove + nxt < PRE_NMS)
    thresh[b] = (uint32_t)((cb << 8) | t);
}

// K5: gather candidate KEYS ONLY (8B each), block-aggregated atomics: one
// atomicAdd per category per block. Strictly-above fills [0, c1); ties fill
// from CAP-1 downward; overflow ties dropped (only above 2096 ties/batch).
__global__ void k_gather(const uint32_t* __restrict__ keys,
                         const uint32_t* __restrict__ thresh,
                         uint32_t* __restrict__ cnts,
                         unsigned long long* __restrict__ cand_sort,
                         int A, int chunks) {
  int b = blockIdx.y;
  int t = threadIdx.x;  // 256
  int lane = t & 63;
  int w = t >> 6;  // wave 0..3
  __shared__ unsigned long long s_mA[MAXCHUNK * 4], s_mT[MAXCHUNK * 4];
  __shared__ uint32_t s_offA[MAXCHUNK * 4], s_offT[MAXCHUNK * 4];
  __shared__ uint32_t s_cA[MAXCHUNK * 4], s_cT[MAXCHUNK * 4];
  __shared__ uint32_t s_baseA, s_baseT;
  uint32_t beta = thresh[b];
  uint32_t kreg[MAXCHUNK];
  int base_a = blockIdx.x * (chunks * 256);
  for (int c = 0; c < chunks; c++) {
    int a = base_a + c * 256 + t;
    bool inb = a < A;
    uint32_t k = inb ? keys[(size_t)b * A + a] : KEY_NEGINF;
    kreg[c] = k;
    uint32_t bk = k >> 16;
    bool fin = (k != KEY_NEGINF);
    unsigned long long mA = __ballot(fin && (bk > beta));
    unsigned long long mT = __ballot(fin && (bk == beta));
    if (lane == 0) {
      s_mA[c * 4 + w] = mA;
      s_mT[c * 4 + w] = mT;
    }
  }
  __syncthreads();
  if (t < chunks * 4) {
    s_cA[t] = (uint32_t)__popcll(s_mA[t]);
    s_cT[t] = (uint32_t)__popcll(s_mT[t]);
  }
  __syncthreads();
  if (t == 0) {  // serial scan over <=44 entries, then ONE atomic per category
    uint32_t accA = 0, accT = 0;
    for (int id = 0; id < chunks * 4; id++) {
      s_offA[id] = accA;
      accA += s_cA[id];
      s_offT[id] = accT;
      accT += s_cT[id];
    }
    s_baseA = accA ? atomicAdd(&cnts[b * CNT_STRIDE + 0], accA) : 0u;
    s_baseT = accT ? atomicAdd(&cnts[b * CNT_STRIDE + 1], accT) : 0u;
  }
  __syncthreads();
  uint32_t baseA = s_baseA, baseT = s_baseT;
  unsigned long long lower = ((unsigned long long)1 << lane) - 1;
  for (int c = 0; c < chunks; c++) {
    int id = c * 4 + w;
    unsigned long long mA = s_mA[id], mT = s_mT[id];
    bool above = (mA >> lane) & 1;
    bool tie = (mT >> lane) & 1;
    if (!(above || tie)) continue;
    int pos;
    if (above) {
      pos = (int)(baseA + s_offA[id] + (uint32_t)__popcll(mA & lower));
      if (pos >= PRE_NMS) continue;  // defensive; cannot happen
    } else {
      pos = CAP - 1 - (int)(baseT + s_offT[id] + (uint32_t)__popcll(mT & lower));
      if (pos < PRE_NMS) continue;  // drop overflow ties
    }
    int a = base_a + c * 256 + t;
    // sort key: (score_key desc, anchor index asc) via descending u64 order
    cand_sort[(size_t)b * CAP + pos] =
        ((unsigned long long)kreg[c] << 32) | (uint32_t)(~(uint32_t)a);
  }
}

// K6a: default-fill selection (pads for degenerate batches; overwritten by
// k_rank for every live rank < SEL). grid = (SEL/256, B).
__global__ void k_fillsel(float4* __restrict__ sel_box,
                          float* __restrict__ sel_score) {
  int b = blockIdx.y;
  int r = blockIdx.x * 256 + threadIdx.x;
  sel_score[(size_t)b * SEL + r] = -INFINITY;
  sel_box[(size_t)b * SEL + r] = make_float4(0.0f, 0.0f, 0.0f, 0.0f);
}

// K6b: enumeration sort. Keys are strictly distinct ((score_key, ~anchor)),
// so rank = #{keys > mine} is the exact descending-sorted position. Each
// thread owns one slot, streams the batch's live slots through LDS broadcast
// tiles, and (if rank < SEL) decodes its box from the embedded anchor index.
// grid = (CAP/256, B). Fully parallel: 256 blocks, no cross-thread deps.
__global__ void k_rank(const unsigned long long* __restrict__ cand_sort,
                       const uint32_t* __restrict__ cnts,
                       const float4* __restrict__ anchors,
                       const float4* __restrict__ deltas,
                       float4* __restrict__ sel_box,
                       float* __restrict__ sel_score, int A) {
  int b = blockIdx.y;
  int t = threadIdx.x;  // 256
  uint32_t c1 = cnts[b * CNT_STRIDE + 0];
  if (c1 > PRE_NMS) c1 = PRE_NMS;
  uint32_t c2 = cnts[b * CNT_STRIDE + 1];
  if (c2 > CAP - PRE_NMS) c2 = CAP - PRE_NMS;
  int loTie = CAP - (int)c2;
  int bs = blockIdx.x * 256;
  if (bs >= (int)c1 && bs + 256 <= loTie) return;  // block fully in dead gap
  int s = bs + t;
  bool live = (s < (int)c1) || (s >= loTie);
  unsigned long long myKey = live ? cand_sort[(size_t)b * CAP + s] : 0ull;
  __shared__ unsigned long long tile[256];
  int rank = 0;
  for (int ts = 0; ts < CAP; ts += 256) {  // tile-skip is block-uniform
    if (ts >= (int)c1 && ts + 256 <= loTie) continue;
    int idx = ts + t;
    bool lv = (idx < (int)c1) || (idx >= loTie);
    __syncthreads();
    tile[t] = lv ? cand_sort[(size_t)b * CAP + idx] : 0ull;
    __syncthreads();
    if (live) {
#pragma unroll 8
      for (int j = 0; j < 256; j++) rank += (tile[j] > myKey) ? 1 : 0;
    }
  }
  if (live && rank < SEL) {
    uint32_t a = ~((uint32_t)myKey);
    float4 box = decode_clip(anchors[a], deltas[(size_t)b * A + a]);
    sel_score[(size_t)b * SEL + rank] = key2f((uint32_t)(myKey >> 32));
    sel_box[(size_t)b * SEL + rank] = box;
  }
}

// K7: suppression bitmask. mask[b][i][jb] bit jj set iff j = jb*64+jj > i,
// j < PRE_NMS, IoU(box_i, box_j) > NMS_THR. Rows in [PRE_NMS, SEL) zeroed
// so k_scanout never reads unwritten workspace.
__global__ void k_nmsmask(const float4* __restrict__ sel_box,
                          unsigned long long* __restrict__ mask) {
  int jb = blockIdx.x;  // col block
  int ib = blockIdx.y;  // row block
  int b = blockIdx.z;
  int t = threadIdx.x;  // 64
  int i = ib * 64 + t;
  if (jb < ib) {  // uniform per block; entire col tile is <= all rows
    mask[((size_t)b * SEL + i) * NW + jb] = 0ull;
    return;
  }
  __shared__ float4 cb[64];
  __shared__ float careb[64];
  int j0 = jb * 64;
  float4 cbx = sel_box[(size_t)b * SEL + j0 + t];
  cb[t] = cbx;
  careb[t] = (cbx.z - cbx.x) * (cbx.w - cbx.y);
  __syncthreads();
  if (i >= PRE_NMS) {  // pad rows: write zeros, never leave stale poison
    mask[((size_t)b * SEL + i) * NW + jb] = 0ull;
    return;
  }
  float4 a = sel_box[(size_t)b * SEL + i];
  float area_a = (a.z - a.x) * (a.w - a.y);
  unsigned long long bits = 0ull;
  int jmax = min(64, PRE_NMS - j0);
  for (int jj = 0; jj < jmax; jj++) {
    int j = j0 + jj;
    if (j <= i) continue;
    float4 bb = cb[jj];
    float ltx = fmaxf(a.x, bb.x), lty = fmaxf(a.y, bb.y);
    float rbx = fminf(a.z, bb.z), rby = fminf(a.w, bb.w);
    float w = fmaxf(rbx - ltx, 0.0f), hgt = fmaxf(rby - lty, 0.0f);
    float inter = w * hgt;
    float iou = inter / (area_a + careb[jj] - inter + 1e-6f);
    if (iou > NMS_THR) bits |= (1ull << jj);
  }
  mask[((size_t)b * SEL + i) * NW + jb] = bits;
}

// K8: one wave per batch. ffs-driven greedy scan over alive rows only.
// Chunk-tile (64 rows x 32 words = 16KB) staged via global_load_lds DMA
// (side-effecting: cannot be sunk/batched by regalloc, zero VGPRs, lands
// during the scan). diag/score for chunk c+1 prefetched during chunk c so
// the scan starts wait-free. Accumulate: 64 ds_read_b64 from the tile
// (lane w reads word w; 2-way bank aliasing = free) ORed into `removed`
// under branchless uniform SGPR masks.
__global__ void __launch_bounds__(64, 1)
k_scanout(const float4* __restrict__ sel_box,
          const float* __restrict__ sel_score,
          const unsigned long long* __restrict__ mask,
          float* __restrict__ out) {
  int b = blockIdx.x;
  int t = threadIdx.x;  // 64 = 1 wave
  int tw = t & 31;
  __shared__ uint32_t keptList[POST_NMS + 64];  // overshoot space
  __shared__ unsigned long long tile[64 * NW];  // 16 KB chunk mask tile
  unsigned long long removed = 0ull;  // lane w<32 owns word w (dup in w+32)
  int kc = 0;
  const unsigned long long* mbase = mask + (size_t)b * SEL * NW;
  const int lastChunk = (PRE_NMS - 1) / 64;  // 31

  // prologue: load chunk 0's diag word + score
  unsigned long long diag = mbase[(size_t)t * NW + 0];
  uint32_t scb = __float_as_uint(sel_score[(size_t)b * SEL + t]);

  int g = t >> 4;                 // DMA row sub-index 0..3
  int cq = (t & 15) * 16;         // DMA byte offset within row (16B/lane)

  for (int chunk = 0; chunk <= lastChunk; chunk++) {
    int rmax = PRE_NMS - chunk * 64;  // rows beyond PRE_NMS excluded
    if (rmax > 64) rmax = 64;
    const unsigned long long* cbase = mbase + (size_t)chunk * 64 * NW;
    // Issue 16 LDS-DMA ops covering the 64x32-word tile (1KB per op, rows
    // 4k..4k+3 each). Destination is linear row-major: lane t of op k writes
    // bytes [k*1024 + g*256 + cq, +16) == row(4k+g) words [2*(t&15), +2).
    {
      const char* gb = (const char*)cbase;
#pragma unroll
      for (int k = 0; k < 16; k++) {
        const void* gp = gb + (size_t)(4 * k + g) * (NW * 8) + cq;
        __builtin_amdgcn_global_load_lds(
            (const __attribute__((address_space(1))) uint32_t*)gp,
            (__attribute__((address_space(3))) uint32_t*)&tile[(size_t)k * 128],
            16, 0, 0);
      }
    }
    // Prefetch next chunk's diag word + score (plain loads, consumed next
    // iteration -> off the serial chain).
    unsigned long long diag_n = 0ull;
    uint32_t scb_n = 0xFF800000u;
    if (chunk < lastChunk) {
      diag_n = mbase[((size_t)((chunk + 1) * 64 + t)) * NW + (chunk + 1)];
      scb_n =
          __float_as_uint(sel_score[(size_t)b * SEL + (chunk + 1) * 64 + t]);
    }
    // score validity for all 64 rows in one ballot (scb loaded last iter)
    unsigned long long vb = __ballot(scb != 0xFF800000u);
    // entry removed word for this chunk
    unsigned long long curw = readlane_u64(removed, chunk);
    unsigned long long range = (rmax >= 64) ? ~0ull : ((1ull << rmax) - 1ull);
    unsigned long long work = ~curw & range;
    unsigned long long keptbits = 0ull;
    while (work) {
      int r = __ffsll((long long)work) - 1;
      keptbits |= (1ull << r);
      unsigned long long d = readlane_u64(diag, r);
      curw |= d;
      unsigned long long low = (2ull << r) - 1ull;  // bits 0..r (r=63 ok)
      work &= ~(curw | low);
    }
    // bookkeeping (off the serial chain)
    unsigned long long kv = keptbits & vb;
    if ((kv >> t) & 1ull) {
      int rank = (int)__popcll(kv & ((1ull << t) - 1ull));
      keptList[kc + rank] = (uint32_t)(chunk * 64 + t);
    }
    kc += (int)__popcll(kv);
    if (kc >= POST_NMS) break;           // future chunks irrelevant
    if (chunk == lastChunk) break;       // no future chunks
    // Tile is needed now: drain the DMA (mostly complete - it overlapped the
    // scan), then accumulate removed from LDS, branchless masked OR.
    asm volatile("s_waitcnt vmcnt(0)" ::: "memory");
    __builtin_amdgcn_sched_barrier(0);
    uint32_t klo = (uint32_t)keptbits;
    uint32_t khi = (uint32_t)(keptbits >> 32);
#pragma unroll
    for (int j = 0; j < 32; j++) {
      unsigned long long mk =
          (unsigned long long)(-(long long)((klo >> j) & 1u));
      removed |= tile[j * NW + tw] & mk;
    }
#pragma unroll
    for (int j = 0; j < 32; j++) {
      unsigned long long mk =
          (unsigned long long)(-(long long)((khi >> j) & 1u));
      removed |= tile[(32 + j) * NW + tw] & mk;
    }
    // All ds_reads consumed above (lgkm waits emitted before the ORs); make
    // sure nothing from the next iteration's DMA slides above this point.
    __builtin_amdgcn_sched_barrier(0);
    diag = diag_n;
    scb = scb_n;
  }
  int kcc = kc < POST_NMS ? kc : POST_NMS;
  __syncthreads();
  for (int r = t; r < POST_NMS; r += 64) {
    float4 bx = make_float4(0.0f, 0.0f, 0.0f, 0.0f);
    float sc = 0.0f;
    if (r < kcc) {
      int i = (int)keptList[r];
      bx = sel_box[(size_t)b * SEL + i];
      sc = sel_score[(size_t)b * SEL + i];
    }
    float* o = out + ((size_t)b * POST_NMS + r) * 5;
    o[0] = bx.x;
    o[1] = bx.y;
    o[2] = bx.z;
    o[3] = bx.w;
    o[4] = sc;
  }
}

extern "C" void kernel_launch(void* const* d_in, const int* in_sizes, int n_in,
                              void* d_out, int out_size, void* d_ws, size_t ws_size,
                              hipStream_t stream) {
  const float* anchors = (const float*)d_in[0];  // (A, 4)
  const float* deltas = (const float*)d_in[1];   // (B, A, 4)
  const float* scores = (const float*)d_in[2];   // (B, A)
  int A = in_sizes[0] / 4;
  int BA = in_sizes[2];
  int B = BA / A;
  float* out = (float*)d_out;

  char* ws = (char*)d_ws;
  size_t off = 0;
  uint32_t* keys = (uint32_t*)(ws + off);
  off += (size_t)BA * 4;
  uint32_t* chist = (uint32_t*)(ws + off);
  off += (size_t)B * 256 * 4;
  uint32_t* fhist = (uint32_t*)(ws + off);
  off += (size_t)B * 256 * 4;
  int* cbArr = (int*)(ws + off);
  off += (size_t)B * 4;
  uint32_t* cumArr = (uint32_t*)(ws + off);
  off += (size_t)B * 4;
  uint32_t* thresh = (uint32_t*)(ws + off);
  off += (size_t)B * 4;
  off = (off + 127) & ~(size_t)127;
  uint32_t* cnts = (uint32_t*)(ws + off);
  off += (size_t)B * CNT_STRIDE * 4;
  off = (off + 15) & ~(size_t)15;
  unsigned long long* cand_sort = (unsigned long long*)(ws + off);
  off += (size_t)B * CAP * 8;
  float4* sel_box = (float4*)(ws + off);
  off += (size_t)B * SEL * 16;
  float* sel_score = (float*)(ws + off);
  off += (size_t)B * SEL * 4;
  unsigned long long* mask = (unsigned long long*)(ws + off);
  off += (size_t)B * SEL * NW * 8;
  // total ~27 MB

  // Block geometry for per-batch streaming kernels: A = 261888 = 256*11*93.
  int chunks = (A % (256 * 11) == 0) ? 11 : 1;
  int bpb = (A + 256 * chunks - 1) / (256 * chunks);  // blocks per batch

  hipMemsetAsync(chist, 0, (size_t)B * 256 * 4 * 2, stream);  // chist+fhist
  k_decode<<<dim3(bpb, B), 256, 0, stream>>>((const float4*)anchors,
                                             (const float4*)deltas, scores,
                                             keys, chist, A, chunks);
  k_coarse<<<B, 256, 0, stream>>>(chist, cbArr, cumArr);
  k_fine<<<dim3(bpb, B), 256, 0, stream>>>(keys, cbArr, fhist, A, chunks);
  k_thresh<<<B, 256, 0, stream>>>(fhist, cbArr, cumArr, thresh, cnts);
  k_gather<<<dim3(bpb, B), 256, 0, stream>>>(keys, thresh, cnts, cand_sort, A,
                                             chunks);
  k_fillsel<<<dim3(SEL / 256, B), 256, 0, stream>>>(sel_box, sel_score);
  k_rank<<<dim3(CAP / 256, B), 256, 0, stream>>>(cand_sort, cnts,
                                                 (const float4*)anchors,
                                                 (const float4*)deltas,
                                                 sel_box, sel_score, A);
  k_nmsmask<<<dim3(NW, SEL / 64, B), 64, 0, stream>>>(sel_box, mask);
  k_scanout<<<B, 64, 0, stream>>>(sel_box, sel_score, mask, out);
}

// Round 6
// 288.801 us; speedup vs baseline: 1.1404x; 1.1321x over previous
//
#include <hip/hip_runtime.h>
#include <stdint.h>
#include <math.h>

// RPN proposal filtering: decode -> clip -> validity mask -> stable top-2000
// -> greedy NMS (IoU > 0.7) -> first 1000 kept -> (B, 1000, 5).
//
// R12 = R11 resubmit (round 5 bench was an infra failure: "container failed
// twice", no compile/test/profile evidence of a kernel defect; hang-risk
// audit found none).
//
// R11: k_scanout's per-row serial bit-chase ELIMINATED. R8-R10 converged at
// 77+-2us under three different memory arrangements -> the serial ffs loop
// (~170cyc x ~1000 kept rows) was the floor. Within a 64-row chunk, greedy
// NMS = grounded extension of an ACYCLIC attack DAG (edges i->j, i<j only),
// whose unique fixpoint is computed by Jacobi iteration
//   K_{n+1}[j] = alive[j] && (colMask[j] & K_n)==0
// in <= chain-depth rounds (~2-5 typical), each round = v_and_b64 + ballot.
// k_nmsmask diagonal blocks now also emit the transposed in-chunk column
// word per row (maskT, 64 ballots per diag block). Cross-chunk suppression
// accumulates as before from a double-buffered LDS-DMA tile. k_fillsel
// folded into k_gather (one fewer launch).

#define IMGF 1024.0f
#define PRE_NMS 2000
#define POST_NMS 1000
#define NMS_THR 0.7f
#define MIN_SZ 16.0f
#define CAP 4096          // candidate buffer per batch
#define SEL 2048          // padded selection stride (>= PRE_NMS)
#define NW (SEL / 64)     // 32 mask words per row
#define CNT_STRIDE 32     // u32s per batch for counters (128 B -> own line)
#define KEY_NEGINF 0x007FFFFFu  // f2key(-inf)
#define MAXCHUNK 12

// Order-preserving float -> u32 key (all floats incl. -inf totally ordered).
__device__ __forceinline__ uint32_t f2key(float f) {
  uint32_t u = __float_as_uint(f);
  return (u & 0x80000000u) ? ~u : (u | 0x80000000u);
}
__device__ __forceinline__ float key2f(uint32_t k) {
  uint32_t u = (k & 0x80000000u) ? (k & 0x7FFFFFFFu) : ~k;
  return __uint_as_float(u);
}

__device__ __forceinline__ unsigned long long readlane_u64(unsigned long long v,
                                                           int lane) {
  unsigned int lo = __builtin_amdgcn_readlane((unsigned int)v, lane);
  unsigned int hi = __builtin_amdgcn_readlane((unsigned int)(v >> 32), lane);
  return ((unsigned long long)hi << 32) | lo;
}

// Mirrors reference _decode + clip, fp32.
__device__ __forceinline__ float4 decode_clip(float4 anc, float4 dlt) {
  float aw = anc.z - anc.x;
  float ah = anc.w - anc.y;
  float ax = anc.x + 0.5f * aw;
  float ay = anc.y + 0.5f * ah;
  float dw = fminf(dlt.z, 4.0f);
  float dh = fminf(dlt.w, 4.0f);
  float px = dlt.x * aw + ax;
  float py = dlt.y * ah + ay;
  float pw = expf(dw) * aw;
  float ph = expf(dh) * ah;
  float x1 = px - 0.5f * pw, y1 = py - 0.5f * ph;
  float x2 = px + 0.5f * pw, y2 = py + 0.5f * ph;
  x1 = fminf(fmaxf(x1, 0.0f), IMGF);
  y1 = fminf(fmaxf(y1, 0.0f), IMGF);
  x2 = fminf(fmaxf(x2, 0.0f), IMGF);
  y2 = fminf(fmaxf(y2, 0.0f), IMGF);
  return make_float4(x1, y1, x2, y2);
}

// K1: decode -> masked-score key; per-block LDS coarse hist of key>>24
// (finite keys only), ballot-match wave aggregation, one aggregated global
// flush per block. grid = (bpb, B).
__global__ void k_decode(const float4* __restrict__ anchors,
                         const float4* __restrict__ deltas,
                         const float* __restrict__ scores,
                         uint32_t* __restrict__ keys,
                         uint32_t* __restrict__ chist,
                         int A, int chunks) {
  int b = blockIdx.y;
  int t = threadIdx.x;  // 256
  int lane = t & 63;
  __shared__ uint32_t shist[256];
  shist[t] = 0;
  __syncthreads();
  int base_a = blockIdx.x * (chunks * 256);
  for (int c = 0; c < chunks; c++) {
    int a = base_a + c * 256 + t;
    bool inb = a < A;
    int ac = inb ? a : (A - 1);
    size_t i = (size_t)b * A + ac;
    float4 box = decode_clip(anchors[ac], deltas[i]);
    bool valid = (box.z - box.x >= MIN_SZ) && (box.w - box.y >= MIN_SZ);
    float ms = valid ? scores[i] : -INFINITY;
    uint32_t k = f2key(ms);
    if (inb) keys[i] = k;
    uint32_t bucket = k >> 24;
    bool fin = inb && (k != KEY_NEGINF);
    // lanes with equal bucket -> one LDS atomic by the leader
    unsigned long long match = __ballot(fin);
#pragma unroll
    for (int bit = 0; bit < 8; bit++) {
      bool hb = (bucket >> bit) & 1;
      unsigned long long bb = __ballot(hb && fin);
      match &= hb ? bb : ~bb;
    }
    if (fin && (__ffsll((long long)match) - 1 == lane))
      atomicAdd(&shist[bucket], (uint32_t)__popcll(match));
  }
  __syncthreads();
  uint32_t v = shist[t];
  if (v) atomicAdd(&chist[b * 256 + t], v);
}

// K2: pick coarse bucket cb s.t. countAbove(cb) < PRE_NMS <= countAbove(cb)+chist[cb].
__global__ void k_coarse(const uint32_t* __restrict__ chist,
                         int* __restrict__ cbArr,
                         uint32_t* __restrict__ cumArr) {
  int b = blockIdx.x;
  int t = threadIdx.x;  // 256
  __shared__ uint32_t sA[256];
  sA[t] = chist[b * 256 + t];
  for (int d = 1; d < 256; d <<= 1) {  // inclusive suffix scan
    __syncthreads();
    uint32_t v = sA[t] + ((t + d < 256) ? sA[t + d] : 0u);
    __syncthreads();
    sA[t] = v;
  }
  __syncthreads();
  if (t == 0 && sA[0] < PRE_NMS) {  // degenerate: < PRE_NMS finite entries
    cbArr[b] = -1;
    cumArr[b] = 0;
  }
  uint32_t nxt = (t < 255) ? sA[t + 1] : 0u;
  if (sA[t] >= PRE_NMS && nxt < PRE_NMS) {
    cbArr[b] = t;
    cumArr[b] = nxt;  // count strictly above coarse bucket t
  }
}

// K3: fine hist of key bits[23:16] for elements whose coarse bucket == cb[b].
__global__ void k_fine(const uint32_t* __restrict__ keys,
                       const int* __restrict__ cbArr,
                       uint32_t* __restrict__ fhist,
                       int A, int chunks) {
  int b = blockIdx.y;
  int t = threadIdx.x;  // 256
  int cb = cbArr[b];
  if (cb < 0) return;
  __shared__ uint32_t shist[256];
  shist[t] = 0;
  __syncthreads();
  int base_a = blockIdx.x * (chunks * 256);
  uint32_t cbu = (uint32_t)cb;
  for (int c = 0; c < chunks; c++) {
    int a = base_a + c * 256 + t;
    if (a >= A) break;
    uint32_t k = keys[(size_t)b * A + a];
    if ((k >> 24) == cbu && k != KEY_NEGINF)
      atomicAdd(&shist[(k >> 16) & 0xFFu], 1u);
  }
  __syncthreads();
  uint32_t v = shist[t];
  if (v) atomicAdd(&fhist[b * 256 + t], v);
}

// K4: final 16-bit threshold beta = (cb<<8)|d:
// count(key>>16 > beta) < PRE_NMS <= count(key>>16 >= beta), finite keys only.
__global__ void k_thresh(const uint32_t* __restrict__ fhist,
                         const int* __restrict__ cbArr,
                         const uint32_t* __restrict__ cumArr,
                         uint32_t* __restrict__ thresh,
                         uint32_t* __restrict__ cnts) {
  int b = blockIdx.x;
  int t = threadIdx.x;  // 256
  __shared__ uint32_t sA[256];
  if (t < 2) cnts[b * CNT_STRIDE + t] = 0;
  int cb = cbArr[b];
  if (cb < 0) {
    if (t == 0) thresh[b] = 0u;
    return;
  }
  uint32_t cumAbove = cumArr[b];
  sA[t] = fhist[b * 256 + t];
  for (int d = 1; d < 256; d <<= 1) {
    __syncthreads();
    uint32_t v = sA[t] + ((t + d < 256) ? sA[t + d] : 0u);
    __syncthreads();
    sA[t] = v;
  }
  __syncthreads();
  uint32_t nxt = (t < 255) ? sA[t + 1] : 0u;
  if (cumAbove + sA[t] >= PRE_NMS && cumAbove + nxt < PRE_NMS)
    thresh[b] = (uint32_t)((cb << 8) | t);
}

// K5: gather candidate KEYS ONLY (8B each), block-aggregated atomics: one
// atomicAdd per category per block. Strictly-above fills [0, c1); ties fill
// from CAP-1 downward; overflow ties dropped (only above 2096 ties/batch).
// R11: first SEL/256 blocks per batch also default-fill sel_box/sel_score
// (was k_fillsel; different buffers, no ordering hazard inside this kernel).
__global__ void k_gather(const uint32_t* __restrict__ keys,
                         const uint32_t* __restrict__ thresh,
                         uint32_t* __restrict__ cnts,
                         unsigned long long* __restrict__ cand_sort,
                         float4* __restrict__ sel_box,
                         float* __restrict__ sel_score,
                         int A, int chunks) {
  int b = blockIdx.y;
  int t = threadIdx.x;  // 256
  int lane = t & 63;
  int w = t >> 6;  // wave 0..3
  if (blockIdx.x < SEL / 256) {  // folded k_fillsel
    int r = blockIdx.x * 256 + t;
    sel_score[(size_t)b * SEL + r] = -INFINITY;
    sel_box[(size_t)b * SEL + r] = make_float4(0.0f, 0.0f, 0.0f, 0.0f);
  }
  __shared__ unsigned long long s_mA[MAXCHUNK * 4], s_mT[MAXCHUNK * 4];
  __shared__ uint32_t s_offA[MAXCHUNK * 4], s_offT[MAXCHUNK * 4];
  __shared__ uint32_t s_cA[MAXCHUNK * 4], s_cT[MAXCHUNK * 4];
  __shared__ uint32_t s_baseA, s_baseT;
  uint32_t beta = thresh[b];
  uint32_t kreg[MAXCHUNK];
  int base_a = blockIdx.x * (chunks * 256);
  for (int c = 0; c < chunks; c++) {
    int a = base_a + c * 256 + t;
    bool inb = a < A;
    uint32_t k = inb ? keys[(size_t)b * A + a] : KEY_NEGINF;
    kreg[c] = k;
    uint32_t bk = k >> 16;
    bool fin = (k != KEY_NEGINF);
    unsigned long long mA = __ballot(fin && (bk > beta));
    unsigned long long mT = __ballot(fin && (bk == beta));
    if (lane == 0) {
      s_mA[c * 4 + w] = mA;
      s_mT[c * 4 + w] = mT;
    }
  }
  __syncthreads();
  if (t < chunks * 4) {
    s_cA[t] = (uint32_t)__popcll(s_mA[t]);
    s_cT[t] = (uint32_t)__popcll(s_mT[t]);
  }
  __syncthreads();
  if (t == 0) {  // serial scan over <=44 entries, then ONE atomic per category
    uint32_t accA = 0, accT = 0;
    for (int id = 0; id < chunks * 4; id++) {
      s_offA[id] = accA;
      accA += s_cA[id];
      s_offT[id] = accT;
      accT += s_cT[id];
    }
    s_baseA = accA ? atomicAdd(&cnts[b * CNT_STRIDE + 0], accA) : 0u;
    s_baseT = accT ? atomicAdd(&cnts[b * CNT_STRIDE + 1], accT) : 0u;
  }
  __syncthreads();
  uint32_t baseA = s_baseA, baseT = s_baseT;
  unsigned long long lower = ((unsigned long long)1 << lane) - 1;
  for (int c = 0; c < chunks; c++) {
    int id = c * 4 + w;
    unsigned long long mA = s_mA[id], mT = s_mT[id];
    bool above = (mA >> lane) & 1;
    bool tie = (mT >> lane) & 1;
    if (!(above || tie)) continue;
    int pos;
    if (above) {
      pos = (int)(baseA + s_offA[id] + (uint32_t)__popcll(mA & lower));
      if (pos >= PRE_NMS) continue;  // defensive; cannot happen
    } else {
      pos = CAP - 1 - (int)(baseT + s_offT[id] + (uint32_t)__popcll(mT & lower));
      if (pos < PRE_NMS) continue;  // drop overflow ties
    }
    int a = base_a + c * 256 + t;
    // sort key: (score_key desc, anchor index asc) via descending u64 order
    cand_sort[(size_t)b * CAP + pos] =
        ((unsigned long long)kreg[c] << 32) | (uint32_t)(~(uint32_t)a);
  }
}

// K6b: enumeration sort. Keys are strictly distinct ((score_key, ~anchor)),
// so rank = #{keys > mine} is the exact descending-sorted position. Each
// thread owns one slot, streams the batch's live slots through LDS broadcast
// tiles, and (if rank < SEL) decodes its box from the embedded anchor index.
// grid = (CAP/256, B). Fully parallel: 256 blocks, no cross-thread deps.
__global__ void k_rank(const unsigned long long* __restrict__ cand_sort,
                       const uint32_t* __restrict__ cnts,
                       const float4* __restrict__ anchors,
                       const float4* __restrict__ deltas,
                       float4* __restrict__ sel_box,
                       float* __restrict__ sel_score, int A) {
  int b = blockIdx.y;
  int t = threadIdx.x;  // 256
  uint32_t c1 = cnts[b * CNT_STRIDE + 0];
  if (c1 > PRE_NMS) c1 = PRE_NMS;
  uint32_t c2 = cnts[b * CNT_STRIDE + 1];
  if (c2 > CAP - PRE_NMS) c2 = CAP - PRE_NMS;
  int loTie = CAP - (int)c2;
  int bs = blockIdx.x * 256;
  if (bs >= (int)c1 && bs + 256 <= loTie) return;  // block fully in dead gap
  int s = bs + t;
  bool live = (s < (int)c1) || (s >= loTie);
  unsigned long long myKey = live ? cand_sort[(size_t)b * CAP + s] : 0ull;
  __shared__ unsigned long long tile[256];
  int rank = 0;
  for (int ts = 0; ts < CAP; ts += 256) {  // tile-skip is block-uniform
    if (ts >= (int)c1 && ts + 256 <= loTie) continue;
    int idx = ts + t;
    bool lv = (idx < (int)c1) || (idx >= loTie);
    __syncthreads();
    tile[t] = lv ? cand_sort[(size_t)b * CAP + idx] : 0ull;
    __syncthreads();
    if (live) {
#pragma unroll 8
      for (int j = 0; j < 256; j++) rank += (tile[j] > myKey) ? 1 : 0;
    }
  }
  if (live && rank < SEL) {
    uint32_t a = ~((uint32_t)myKey);
    float4 box = decode_clip(anchors[a], deltas[(size_t)b * A + a]);
    sel_score[(size_t)b * SEL + rank] = key2f((uint32_t)(myKey >> 32));
    sel_box[(size_t)b * SEL + rank] = box;
  }
}

// K7: suppression bitmask. mask[b][i][jb] bit jj set iff j = jb*64+jj > i,
// j < PRE_NMS, IoU(box_i, box_j) > NMS_THR. Rows in [PRE_NMS, SEL) zeroed.
// R11: diagonal blocks (jb==ib) additionally emit the TRANSPOSED in-chunk
// column word: maskT[b][i] bit ii set iff in-chunk row ii (< i's lane)
// suppresses i. Pad rows flow through naturally (zero boxes -> IoU 0 ->
// bits 0 -> maskT 0).
__global__ void k_nmsmask(const float4* __restrict__ sel_box,
                          unsigned long long* __restrict__ mask,
                          unsigned long long* __restrict__ maskT) {
  int jb = blockIdx.x;  // col block
  int ib = blockIdx.y;  // row block
  int b = blockIdx.z;
  int t = threadIdx.x;  // 64
  int i = ib * 64 + t;
  if (jb < ib) {  // uniform per block; entire col tile is <= all rows
    mask[((size_t)b * SEL + i) * NW + jb] = 0ull;
    return;
  }
  __shared__ float4 cb[64];
  __shared__ float careb[64];
  int j0 = jb * 64;
  float4 cbx = sel_box[(size_t)b * SEL + j0 + t];
  cb[t] = cbx;
  careb[t] = (cbx.z - cbx.x) * (cbx.w - cbx.y);
  __syncthreads();
  bool pad = (i >= PRE_NMS);
  if (pad && jb != ib) {  // only possible for ib==31==jb; keep defensive
    mask[((size_t)b * SEL + i) * NW + jb] = 0ull;
    return;
  }
  float4 a = sel_box[(size_t)b * SEL + i];
  float area_a = (a.z - a.x) * (a.w - a.y);
  unsigned long long bits = 0ull;
  int jmax = min(64, PRE_NMS - j0);
  if (!pad) {
    for (int jj = 0; jj < jmax; jj++) {
      int j = j0 + jj;
      if (j <= i) continue;
      float4 bb = cb[jj];
      float ltx = fmaxf(a.x, bb.x), lty = fmaxf(a.y, bb.y);
      float rbx = fminf(a.z, bb.z), rby = fminf(a.w, bb.w);
      float w = fmaxf(rbx - ltx, 0.0f), hgt = fmaxf(rby - lty, 0.0f);
      float inter = w * hgt;
      float iou = inter / (area_a + careb[jj] - inter + 1e-6f);
      if (iou > NMS_THR) bits |= (1ull << jj);
    }
  }
  mask[((size_t)b * SEL + i) * NW + jb] = bits;
  if (jb == ib) {  // transpose the 64x64 diagonal block via ballots
    unsigned long long myT = 0ull;
#pragma unroll 1
    for (int jj = 0; jj < 64; jj++) {
      unsigned long long colw = __ballot((bits >> jj) & 1ull);
      if (t == jj) myT = colw;
    }
    maskT[(size_t)b * SEL + i] = myT;
  }
}

// K8: one wave per batch. Per 64-row chunk: greedy NMS = grounded extension
// of the acyclic in-chunk attack DAG, computed by Jacobi iteration
//   K <- ballot(alive && (colm & K)==0)
// (unique fixpoint; converges in <= chain depth rounds, each ~1 ballot).
// NO per-row serial loop. Cross-chunk `removed` accumulates from a
// DOUBLE-BUFFERED LDS-DMA tile: DMA for chunk c+1 issued at top of chunk c,
// accumulate reads chunk c's buffer (landed during previous chunk).
// colm/score for c+1 prefetched during c.
__global__ void __launch_bounds__(64, 1)
k_scanout(const float4* __restrict__ sel_box,
          const float* __restrict__ sel_score,
          const unsigned long long* __restrict__ mask,
          const unsigned long long* __restrict__ maskT,
          float* __restrict__ out) {
  int b = blockIdx.x;
  int t = threadIdx.x;  // 64 = 1 wave
  int tw = t & 31;
  __shared__ uint32_t keptList[POST_NMS + 64];   // overshoot space
  __shared__ unsigned long long tile[2][64 * NW];  // 2 x 16 KB mask tiles
  unsigned long long removed = 0ull;  // lane w<32 owns word w (dup in w+32)
  int kc = 0;
  const unsigned long long* mbase = mask + (size_t)b * SEL * NW;
  const unsigned long long* tbase = maskT + (size_t)b * SEL;
  const int lastChunk = (PRE_NMS - 1) / 64;  // 31
  int g = t >> 4;          // DMA row sub-index 0..3
  int cq = (t & 15) * 16;  // DMA byte offset within row (16B/lane)

  // prologue: DMA chunk 0 -> tile[0]; load chunk 0's colm + score
  {
    const char* gb = (const char*)mbase;
#pragma unroll
    for (int k = 0; k < 16; k++) {
      const void* gp = gb + (size_t)(4 * k + g) * (NW * 8) + cq;
      __builtin_amdgcn_global_load_lds(
          (const __attribute__((address_space(1))) uint32_t*)gp,
          (__attribute__((address_space(3))) uint32_t*)&tile[0][(size_t)k * 128],
          16, 0, 0);
    }
  }
  unsigned long long colm = tbase[t];
  uint32_t scb = __float_as_uint(sel_score[(size_t)b * SEL + t]);

  for (int chunk = 0; chunk <= lastChunk; chunk++) {
    int cur = chunk & 1;
    // issue DMA for chunk+1 into the other buffer + prefetch its colm/score
    unsigned long long colm_n = 0ull;
    uint32_t scb_n = 0xFF800000u;
    if (chunk < lastChunk) {
      const char* gb = (const char*)(mbase + (size_t)(chunk + 1) * 64 * NW);
#pragma unroll
      for (int k = 0; k < 16; k++) {
        const void* gp = gb + (size_t)(4 * k + g) * (NW * 8) + cq;
        __builtin_amdgcn_global_load_lds(
            (const __attribute__((address_space(1))) uint32_t*)gp,
            (__attribute__((address_space(3))) uint32_t*)
                &tile[cur ^ 1][(size_t)k * 128],
            16, 0, 0);
      }
      colm_n = tbase[(chunk + 1) * 64 + t];
      scb_n =
          __float_as_uint(sel_score[(size_t)b * SEL + (chunk + 1) * 64 + t]);
    }
    int rmax = PRE_NMS - chunk * 64;
    if (rmax > 64) rmax = 64;
    unsigned long long vb = __ballot(scb != 0xFF800000u);
    unsigned long long curw = readlane_u64(removed, chunk);
    unsigned long long range = (rmax >= 64) ? ~0ull : ((1ull << rmax) - 1ull);
    unsigned long long alive0 = ~curw & range;
    // Jacobi fixpoint: K_{n+1}[j] = alive0[j] && (colm[j] & K_n)==0.
    // Acyclic forward DAG -> unique fixpoint == sequential greedy result;
    // terminates in <= 64 rounds (typically 2-5).
    unsigned long long K = alive0;
    bool aliveb = (alive0 >> t) & 1ull;
#pragma unroll 1
    for (int it = 0; it < 64; ++it) {
      bool deadb = (colm & K) != 0ull;
      unsigned long long Kn = __ballot(aliveb && !deadb);
      if (Kn == K) break;
      K = Kn;
    }
    unsigned long long keptbits = K;
    // bookkeeping: lane-parallel keptList append via popcount rank
    unsigned long long kv = keptbits & vb;
    if ((kv >> t) & 1ull) {
      int rank = (int)__popcll(kv & ((1ull << t) - 1ull));
      keptList[kc + rank] = (uint32_t)(chunk * 64 + t);
    }
    kc += (int)__popcll(kv);
    if (kc >= POST_NMS) break;      // future chunks irrelevant
    if (chunk == lastChunk) break;  // no future chunks
    // Drain chunk's tile DMA (issued LAST iteration; fully overlapped).
    // Newest 18 VMEM ops (this iteration's 16 DMA + colm_n + scb_n) may
    // remain outstanding.
    asm volatile("s_waitcnt vmcnt(18)" ::: "memory");
    __builtin_amdgcn_sched_barrier(0);
    // accumulate removed: branchless masked OR (uniform SGPR masks)
    uint32_t klo = (uint32_t)keptbits;
    uint32_t khi = (uint32_t)(keptbits >> 32);
#pragma unroll
    for (int j = 0; j < 32; j++) {
      unsigned long long mk =
          (unsigned long long)(-(long long)((klo >> j) & 1u));
      removed |= tile[cur][j * NW + tw] & mk;
    }
#pragma unroll
    for (int j = 0; j < 32; j++) {
      unsigned long long mk =
          (unsigned long long)(-(long long)((khi >> j) & 1u));
      removed |= tile[cur][(32 + j) * NW + tw] & mk;
    }
    // keep next iteration's DMA (overwrites tile[cur]) below these ds_reads
    __builtin_amdgcn_sched_barrier(0);
    colm = colm_n;
    scb = scb_n;
  }
  int kcc = kc < POST_NMS ? kc : POST_NMS;
  __syncthreads();
  for (int r = t; r < POST_NMS; r += 64) {
    float4 bx = make_float4(0.0f, 0.0f, 0.0f, 0.0f);
    float sc = 0.0f;
    if (r < kcc) {
      int i = (int)keptList[r];
      bx = sel_box[(size_t)b * SEL + i];
      sc = sel_score[(size_t)b * SEL + i];
    }
    float* o = out + ((size_t)b * POST_NMS + r) * 5;
    o[0] = bx.x;
    o[1] = bx.y;
    o[2] = bx.z;
    o[3] = bx.w;
    o[4] = sc;
  }
}

extern "C" void kernel_launch(void* const* d_in, const int* in_sizes, int n_in,
                              void* d_out, int out_size, void* d_ws, size_t ws_size,
                              hipStream_t stream) {
  const float* anchors = (const float*)d_in[0];  // (A, 4)
  const float* deltas = (const float*)d_in[1];   // (B, A, 4)
  const float* scores = (const float*)d_in[2];   // (B, A)
  int A = in_sizes[0] / 4;
  int BA = in_sizes[2];
  int B = BA / A;
  float* out = (float*)d_out;

  char* ws = (char*)d_ws;
  size_t off = 0;
  uint32_t* keys = (uint32_t*)(ws + off);
  off += (size_t)BA * 4;
  uint32_t* chist = (uint32_t*)(ws + off);
  off += (size_t)B * 256 * 4;
  uint32_t* fhist = (uint32_t*)(ws + off);
  off += (size_t)B * 256 * 4;
  int* cbArr = (int*)(ws + off);
  off += (size_t)B * 4;
  uint32_t* cumArr = (uint32_t*)(ws + off);
  off += (size_t)B * 4;
  uint32_t* thresh = (uint32_t*)(ws + off);
  off += (size_t)B * 4;
  off = (off + 127) & ~(size_t)127;
  uint32_t* cnts = (uint32_t*)(ws + off);
  off += (size_t)B * CNT_STRIDE * 4;
  off = (off + 15) & ~(size_t)15;
  unsigned long long* cand_sort = (unsigned long long*)(ws + off);
  off += (size_t)B * CAP * 8;
  float4* sel_box = (float4*)(ws + off);
  off += (size_t)B * SEL * 16;
  float* sel_score = (float*)(ws + off);
  off += (size_t)B * SEL * 4;
  unsigned long long* mask = (unsigned long long*)(ws + off);
  off += (size_t)B * SEL * NW * 8;
  unsigned long long* maskT = (unsigned long long*)(ws + off);
  off += (size_t)B * SEL * 8;  // 256 KB
  // total ~27.3 MB

  // Block geometry for per-batch streaming kernels: A = 261888 = 256*11*93.
  int chunks = (A % (256 * 11) == 0) ? 11 : 1;
  int bpb = (A + 256 * chunks - 1) / (256 * chunks);  // blocks per batch

  hipMemsetAsync(chist, 0, (size_t)B * 256 * 4 * 2, stream);  // chist+fhist
  k_decode<<<dim3(bpb, B), 256, 0, stream>>>((const float4*)anchors,
                                             (const float4*)deltas, scores,
                                             keys, chist, A, chunks);
  k_coarse<<<B, 256, 0, stream>>>(chist, cbArr, cumArr);
  k_fine<<<dim3(bpb, B), 256, 0, stream>>>(keys, cbArr, fhist, A, chunks);
  k_thresh<<<B, 256, 0, stream>>>(fhist, cbArr, cumArr, thresh, cnts);
  k_gather<<<dim3(bpb, B), 256, 0, stream>>>(keys, thresh, cnts, cand_sort,
                                             sel_box, sel_score, A, chunks);
  k_rank<<<dim3(CAP / 256, B), 256, 0, stream>>>(cand_sort, cnts,
                                                 (const float4*)anchors,
                                                 (const float4*)deltas,
                                                 sel_box, sel_score, A);
  k_nmsmask<<<dim3(NW, SEL / 64, B), 64, 0, stream>>>(sel_box, mask, maskT);
  k_scanout<<<B, 64, 0, stream>>>(sel_box, sel_score, mask, maskT, out);
}